// Round 1
// baseline (223.896 us; speedup 1.0000x reference)
//
#include <hip/hip_runtime.h>
#include <math.h>

#define NQ 14
#define DIM (1 << NQ)        // 16384 amplitudes
#define NLAYERS 3
#define BATCH 256
#define NT 1024              // threads per block (16 waves)

__global__ __launch_bounds__(NT) void qsim_kernel(const float* __restrict__ x,
                                                  const float* __restrict__ w,
                                                  float* __restrict__ out) {
    __shared__ float sRe[DIM];   // 64 KB
    __shared__ float sIm[DIM];   // 64 KB
    __shared__ float red[NT / 64][NQ];

    const int b = blockIdx.x;
    const int tid = threadIdx.x;

    // --- init |0...0> ---
    for (int i = tid; i < DIM; i += NT) { sRe[i] = 0.0f; sIm[i] = 0.0f; }
    if (tid == 0) sRe[0] = 1.0f;
    __syncthreads();

    // --- AngleEmbedding: RY(tanh(x)*pi) on each qubit (per-sample angles) ---
    for (int q = 0; q < NQ; ++q) {
        const float th = tanhf(x[b * NQ + q]) * ((float)M_PI * 0.5f);
        const float c = cosf(th), s = sinf(th);
        const int pt = NQ - 1 - q;        // bit position of qubit q
        const int mask = 1 << pt;
        for (int k = tid; k < DIM / 2; k += NT) {
            const int i0 = ((k >> pt) << (pt + 1)) | (k & (mask - 1));
            const int i1 = i0 | mask;
            const float r0 = sRe[i0], m0 = sIm[i0];
            const float r1 = sRe[i1], m1 = sIm[i1];
            // RY: [[c,-s],[s,c]] (real)
            sRe[i0] = c * r0 - s * r1;  sIm[i0] = c * m0 - s * m1;
            sRe[i1] = s * r0 + c * r1;  sIm[i1] = s * m0 + c * m1;
        }
        __syncthreads();
    }

    // --- BasicEntanglerLayers ---
    for (int l = 0; l < NLAYERS; ++l) {
        // RX(w[l][q]) on each wire
        for (int q = 0; q < NQ; ++q) {
            const float th = w[l * NQ + q] * 0.5f;
            const float c = cosf(th), s = sinf(th);
            const int pt = NQ - 1 - q;
            const int mask = 1 << pt;
            for (int k = tid; k < DIM / 2; k += NT) {
                const int i0 = ((k >> pt) << (pt + 1)) | (k & (mask - 1));
                const int i1 = i0 | mask;
                const float r0 = sRe[i0], m0 = sIm[i0];
                const float r1 = sRe[i1], m1 = sIm[i1];
                // RX: [[c, -i s], [-i s, c]]
                sRe[i0] = c * r0 + s * m1;   sIm[i0] = c * m0 - s * r1;
                sRe[i1] = s * m0 + c * r1;   sIm[i1] = -s * r0 + c * m1;
            }
            __syncthreads();
        }
        // CNOT ring: control q -> target (q+1)%NQ
        for (int q = 0; q < NQ; ++q) {
            const int t = (q + 1) % NQ;
            const int pc = NQ - 1 - q;
            const int pt = NQ - 1 - t;
            const int cmask = 1 << pc, tmask = 1 << pt;
            const int lo = (pc < pt) ? pc : pt;
            const int hi = (pc < pt) ? pt : pc;
            // iterate indices with control=1, target=0 (DIM/4 of them), swap target pair
            for (int k = tid; k < DIM / 4; k += NT) {
                int i = k;
                i = ((i >> lo) << (lo + 1)) | (i & ((1 << lo) - 1));  // insert 0 at lo
                i = ((i >> hi) << (hi + 1)) | (i & ((1 << hi) - 1));  // insert 0 at hi
                i |= cmask;                 // control = 1, target = 0
                const int j = i | tmask;    // target = 1
                const float r = sRe[i], m = sIm[i];
                sRe[i] = sRe[j];  sIm[i] = sIm[j];
                sRe[j] = r;       sIm[j] = m;
            }
            __syncthreads();
        }
    }

    // --- expvals <Z_q> = P(bit_q=0) - P(bit_q=1) ---
    float ev[NQ];
#pragma unroll
    for (int q = 0; q < NQ; ++q) ev[q] = 0.0f;
    for (int i = tid; i < DIM; i += NT) {
        const float p = sRe[i] * sRe[i] + sIm[i] * sIm[i];
#pragma unroll
        for (int q = 0; q < NQ; ++q) {
            const int pt = NQ - 1 - q;
            ev[q] += ((i >> pt) & 1) ? -p : p;
        }
    }
    // wave-level reduction (64 lanes)
#pragma unroll
    for (int q = 0; q < NQ; ++q) {
        for (int off = 32; off > 0; off >>= 1)
            ev[q] += __shfl_down(ev[q], off);
    }
    const int wave = tid >> 6, lane = tid & 63;
    if (lane == 0) {
#pragma unroll
        for (int q = 0; q < NQ; ++q) red[wave][q] = ev[q];
    }
    __syncthreads();
    if (tid < NQ) {
        float acc = 0.0f;
#pragma unroll
        for (int wv = 0; wv < NT / 64; ++wv) acc += red[wv][tid];
        out[b * NQ + tid] = acc;
    }
}

extern "C" void kernel_launch(void* const* d_in, const int* in_sizes, int n_in,
                              void* d_out, int out_size, void* d_ws, size_t ws_size,
                              hipStream_t stream) {
    const float* x = (const float*)d_in[0];        // (256, 14) float32
    const float* w = (const float*)d_in[1];        // (3, 14) float32
    float* out = (float*)d_out;                    // (256, 14) float32
    qsim_kernel<<<BATCH, NT, 0, stream>>>(x, w, out);
}

// Round 2
// 110.205 us; speedup vs baseline: 2.0316x; 2.0316x over previous
//
#include <hip/hip_runtime.h>
#include <math.h>

#define NQ 14
#define DIM (1 << NQ)      // 16384 amplitudes
#define NT 512             // threads per block (8 waves)
#define TA 32              // amplitudes per thread (5-bit tile)
#define NW (NT / 64)

// Bank swizzle: XOR low-5 index bits with bits [9:5]. Verified per-round to give
// <=2-way bank aliasing (free) for every tile pattern used below.
__host__ __device__ constexpr int swz(int idx) { return idx ^ ((idx >> 5) & 31); }

// Tile over 5 bit-positions P0..P4 (j-bit k lives at position Pk). The other 9
// index bits come from the thread id, scattered ascending into the complement.
template <int P0, int P1, int P2, int P3, int P4>
struct Tile {
    static constexpr int PMASK = (1 << P0) | (1 << P1) | (1 << P2) | (1 << P3) | (1 << P4);
    static __device__ __forceinline__ int base_idx(int t) {
        int idx = 0, tb = 0;
#pragma unroll
        for (int p = 0; p < NQ; ++p) {
            if (!((PMASK >> p) & 1)) { idx |= ((t >> tb) & 1) << p; ++tb; }
        }
        return idx;
    }
    static constexpr int off(int j) {
        return (((j >> 0) & 1) << P0) | (((j >> 1) & 1) << P1) | (((j >> 2) & 1) << P2) |
               (((j >> 3) & 1) << P3) | (((j >> 4) & 1) << P4);
    }
};

template <class T>
__device__ __forceinline__ void load_tile(const float2* s, int pb, float* re, float* im) {
#pragma unroll
    for (int j = 0; j < TA; ++j) {
        float2 v = s[pb ^ swz(T::off(j))];
        re[j] = v.x; im[j] = v.y;
    }
}
template <class T>
__device__ __forceinline__ void store_tile(float2* s, int pb, const float* re, const float* im) {
#pragma unroll
    for (int j = 0; j < TA; ++j) s[pb ^ swz(T::off(j))] = make_float2(re[j], im[j]);
}

// RY: [[c,-s],[s,c]] on local bit LB (register-only)
template <int LB>
__device__ __forceinline__ void g_ry(float* re, float* im, float c, float s) {
#pragma unroll
    for (int j = 0; j < TA; ++j) {
        if (j & (1 << LB)) continue;
        const int k = j | (1 << LB);
        float r0 = re[j], i0 = im[j], r1 = re[k], i1 = im[k];
        re[j] = c * r0 - s * r1;  im[j] = c * i0 - s * i1;
        re[k] = s * r0 + c * r1;  im[k] = s * i0 + c * i1;
    }
}
// RX: [[c,-is],[-is,c]]
template <int LB>
__device__ __forceinline__ void g_rx(float* re, float* im, float c, float s) {
#pragma unroll
    for (int j = 0; j < TA; ++j) {
        if (j & (1 << LB)) continue;
        const int k = j | (1 << LB);
        float r0 = re[j], i0 = im[j], r1 = re[k], i1 = im[k];
        re[j] = c * r0 + s * i1;  im[j] = c * i0 - s * r1;
        re[k] = c * r1 + s * i0;  im[k] = c * i1 - s * r0;
    }
}
// CNOT control local-bit LC, target local-bit LT: pure register permutation
template <int LC, int LT>
__device__ __forceinline__ void g_cnot(float* re, float* im) {
#pragma unroll
    for (int j = 0; j < TA; ++j) {
        if (!((j >> LC) & 1) || ((j >> LT) & 1)) continue;
        const int k = j | (1 << LT);
        float tr = re[j], ti = im[j];
        re[j] = re[k]; im[j] = im[k];
        re[k] = tr;    im[k] = ti;
    }
}

__global__ __launch_bounds__(NT, 2) void qsim_kernel(const float* __restrict__ x,
                                                     const float* __restrict__ w,
                                                     float* __restrict__ out) {
    __shared__ float2 sSt[DIM];            // 128 KB interleaved (re,im)
    __shared__ float sC[56], sS[56];       // gate cos/sin: [0..13]=RY embed, 14+l*14+q = RX
    __shared__ float sRed[NW][NQ];

    const int tid = threadIdx.x;
    const int b = blockIdx.x;

    if (tid < 14) {
        float th = tanhf(x[b * NQ + tid]) * 1.57079632679489662f;  // tanh(x)*pi*0.5
        sC[tid] = cosf(th); sS[tid] = sinf(th);
    } else if (tid < 56) {
        float th = w[tid - 14] * 0.5f;
        sC[tid] = cosf(th); sS[tid] = sinf(th);
    }
    __syncthreads();

    // qubit q lives at bit position pt = 13-q
    using TE1 = Tile<13, 12, 11, 10, 9>;   // q0..q4
    using TE2 = Tile<8, 7, 6, 5, 4>;       // q5..q9
    using TE3 = Tile<3, 2, 1, 0, 13>;      // q10..q13 (+bit13)
    using TR2 = Tile<9, 8, 7, 6, 5>;
    using TR3 = Tile<5, 4, 3, 2, 1>;

    float re[TA], im[TA];

    // ---- E1: |0..0> + RY q0..q4 (bits 13..9) ----
#pragma unroll
    for (int j = 0; j < TA; ++j) { re[j] = 0.f; im[j] = 0.f; }
    if (tid == 0) re[0] = 1.f;
    g_ry<0>(re, im, sC[0], sS[0]);
    g_ry<1>(re, im, sC[1], sS[1]);
    g_ry<2>(re, im, sC[2], sS[2]);
    g_ry<3>(re, im, sC[3], sS[3]);
    g_ry<4>(re, im, sC[4], sS[4]);
    store_tile<TE1>(sSt, swz(TE1::base_idx(tid)), re, im);
    __syncthreads();

    // ---- E2: RY q5..q9 (bits 8..4) ----
    {
        int pb = swz(TE2::base_idx(tid));
        load_tile<TE2>(sSt, pb, re, im);
        g_ry<0>(re, im, sC[5], sS[5]);
        g_ry<1>(re, im, sC[6], sS[6]);
        g_ry<2>(re, im, sC[7], sS[7]);
        g_ry<3>(re, im, sC[8], sS[8]);
        g_ry<4>(re, im, sC[9], sS[9]);
        store_tile<TE2>(sSt, pb, re, im);
    }
    __syncthreads();

    // ---- E3: RY q10..q13 (bits 3..0) ----
    {
        int pb = swz(TE3::base_idx(tid));
        load_tile<TE3>(sSt, pb, re, im);
        g_ry<0>(re, im, sC[10], sS[10]);
        g_ry<1>(re, im, sC[11], sS[11]);
        g_ry<2>(re, im, sC[12], sS[12]);
        g_ry<3>(re, im, sC[13], sS[13]);
        store_tile<TE3>(sSt, pb, re, im);
    }
    __syncthreads();

    // ---- entangler layers: RX all wires then CNOT ring (13,12)(12,11)..(1,0)(0,13) ----
#pragma unroll 1
    for (int l = 0; l < 3; ++l) {
        const int s0 = 14 + l * NQ;
        // R1: bits 13..9 — RX q0..q4 + CNOT(13,12)(12,11)(11,10)(10,9)
        {
            int pb = swz(TE1::base_idx(tid));
            load_tile<TE1>(sSt, pb, re, im);
            g_rx<0>(re, im, sC[s0 + 0], sS[s0 + 0]);
            g_rx<1>(re, im, sC[s0 + 1], sS[s0 + 1]);
            g_rx<2>(re, im, sC[s0 + 2], sS[s0 + 2]);
            g_rx<3>(re, im, sC[s0 + 3], sS[s0 + 3]);
            g_rx<4>(re, im, sC[s0 + 4], sS[s0 + 4]);
            g_cnot<0, 1>(re, im);
            g_cnot<1, 2>(re, im);
            g_cnot<2, 3>(re, im);
            g_cnot<3, 4>(re, im);
            store_tile<TE1>(sSt, pb, re, im);
        }
        __syncthreads();
        // R2: bits 9..5 — RX q5..q8 (bits 8..5) + CNOT(9,8)(8,7)(7,6)(6,5)
        {
            int pb = swz(TR2::base_idx(tid));
            load_tile<TR2>(sSt, pb, re, im);
            g_rx<1>(re, im, sC[s0 + 5], sS[s0 + 5]);
            g_rx<2>(re, im, sC[s0 + 6], sS[s0 + 6]);
            g_rx<3>(re, im, sC[s0 + 7], sS[s0 + 7]);
            g_rx<4>(re, im, sC[s0 + 8], sS[s0 + 8]);
            g_cnot<0, 1>(re, im);
            g_cnot<1, 2>(re, im);
            g_cnot<2, 3>(re, im);
            g_cnot<3, 4>(re, im);
            store_tile<TR2>(sSt, pb, re, im);
        }
        __syncthreads();
        // R3: bits 5..1 — RX q9..q12 (bits 4..1) + CNOT(5,4)(4,3)(3,2)(2,1)
        {
            int pb = swz(TR3::base_idx(tid));
            load_tile<TR3>(sSt, pb, re, im);
            g_rx<1>(re, im, sC[s0 + 9], sS[s0 + 9]);
            g_rx<2>(re, im, sC[s0 + 10], sS[s0 + 10]);
            g_rx<3>(re, im, sC[s0 + 11], sS[s0 + 11]);
            g_rx<4>(re, im, sC[s0 + 12], sS[s0 + 12]);
            g_cnot<0, 1>(re, im);
            g_cnot<1, 2>(re, im);
            g_cnot<2, 3>(re, im);
            g_cnot<3, 4>(re, im);
            store_tile<TR3>(sSt, pb, re, im);
        }
        __syncthreads();
        // R4: bits {3,2,1,0,13} — RX q13 (bit0=LB3) + CNOT(1,0)=<LB2,LB3> + CNOT(0,13)=<LB3,LB4>
        {
            int pb = swz(TE3::base_idx(tid));
            load_tile<TE3>(sSt, pb, re, im);
            g_rx<3>(re, im, sC[s0 + 13], sS[s0 + 13]);
            g_cnot<2, 3>(re, im);
            g_cnot<3, 4>(re, im);
            if (l < 2) store_tile<TE3>(sSt, pb, re, im);
        }
        if (l < 2) __syncthreads();
    }

    // ---- expvals straight from the final register tile (TE3 tiling) ----
    float Stot = 0.f, Sl0 = 0.f, Sl1 = 0.f, Sl2 = 0.f, Sl3 = 0.f, Sl4 = 0.f;
#pragma unroll
    for (int j = 0; j < TA; ++j) {
        float pj = re[j] * re[j] + im[j] * im[j];
        Stot += pj;
        Sl0 += ((j >> 0) & 1) ? -pj : pj;  // bit 3
        Sl1 += ((j >> 1) & 1) ? -pj : pj;  // bit 2
        Sl2 += ((j >> 2) & 1) ? -pj : pj;  // bit 1
        Sl3 += ((j >> 3) & 1) ? -pj : pj;  // bit 0
        Sl4 += ((j >> 4) & 1) ? -pj : pj;  // bit 13
    }
    const int base = TE3::base_idx(tid);   // bits 4..12 come from tid
    float ev[NQ];
#pragma unroll
    for (int q = 0; q < NQ; ++q) {
        const int pt = NQ - 1 - q;
        float v;
        if (pt == 13)     v = Sl4;
        else if (pt == 3) v = Sl0;
        else if (pt == 2) v = Sl1;
        else if (pt == 1) v = Sl2;
        else if (pt == 0) v = Sl3;
        else v = ((base >> pt) & 1) ? -Stot : Stot;
        ev[q] = v;
    }
#pragma unroll
    for (int q = 0; q < NQ; ++q) {
#pragma unroll
        for (int o = 32; o > 0; o >>= 1) ev[q] += __shfl_down(ev[q], o);
    }
    const int wv = tid >> 6, ln = tid & 63;
    if (ln == 0) {
#pragma unroll
        for (int q = 0; q < NQ; ++q) sRed[wv][q] = ev[q];
    }
    __syncthreads();
    if (tid < NQ) {
        float acc = 0.f;
#pragma unroll
        for (int k = 0; k < NW; ++k) acc += sRed[k][tid];
        out[b * NQ + tid] = acc;
    }
}

extern "C" void kernel_launch(void* const* d_in, const int* in_sizes, int n_in,
                              void* d_out, int out_size, void* d_ws, size_t ws_size,
                              hipStream_t stream) {
    const float* x = (const float*)d_in[0];   // (256, 14) float32
    const float* w = (const float*)d_in[1];   // (3, 14) float32
    float* out = (float*)d_out;               // (256, 14) float32
    qsim_kernel<<<256, NT, 0, stream>>>(x, w, out);
}

// Round 3
// 98.621 us; speedup vs baseline: 2.2703x; 1.1175x over previous
//
#include <hip/hip_runtime.h>
#include <math.h>

#define NQ 14
#define DIM (1 << NQ)      // 16384 amplitudes
#define NT 1024            // 16 waves per block
#define TA 16              // amplitudes per thread (4-bit tile)
#define NW (NT / 64)

// Linear bank swizzle: phys = idx ^ ((idx>>5)&31). swz(a^b)=swz(a)^swz(b), so
// per-element address = swz(base) ^ swz(off(j)) with swz(off(j)) compile-time.
// Verified analytically: every round's wave access is uniform mod 16 bank-pairs
// -> conflict-free b64.
__host__ __device__ constexpr int swz(int idx) { return idx ^ ((idx >> 5) & 31); }

// Tile over 4 bit-positions; local j-bit k lives at global bit Pk. The other
// 10 index bits come from tid, scattered ascending into the complement.
template <int P0, int P1, int P2, int P3>
struct Tile4 {
    static constexpr int PMASK = (1 << P0) | (1 << P1) | (1 << P2) | (1 << P3);
    static __device__ __forceinline__ int base_idx(int t) {
        int idx = 0, tb = 0;
#pragma unroll
        for (int p = 0; p < NQ; ++p)
            if (!((PMASK >> p) & 1)) { idx |= ((t >> tb) & 1) << p; ++tb; }
        return idx;
    }
    static constexpr int off(int j) {
        return ((j & 1) << P0) | (((j >> 1) & 1) << P1) |
               (((j >> 2) & 1) << P2) | (((j >> 3) & 1) << P3);
    }
};

template <class T>
__device__ __forceinline__ void load_tile(const float2* s, int pb, float* re, float* im) {
#pragma unroll
    for (int j = 0; j < TA; ++j) {
        float2 v = s[pb ^ swz(T::off(j))];
        re[j] = v.x; im[j] = v.y;
    }
}
template <class T>
__device__ __forceinline__ void store_tile(float2* s, int pb, const float* re, const float* im) {
#pragma unroll
    for (int j = 0; j < TA; ++j)
        s[pb ^ swz(T::off(j))] = make_float2(re[j], im[j]);
}

// RY: [[c,-s],[s,c]] on local bit LB (register-only)
template <int LB>
__device__ __forceinline__ void g_ry(float* re, float* im, float c, float s) {
#pragma unroll
    for (int j = 0; j < TA; ++j) {
        if (j & (1 << LB)) continue;
        const int k = j | (1 << LB);
        float r0 = re[j], i0 = im[j], r1 = re[k], i1 = im[k];
        re[j] = c * r0 - s * r1;  im[j] = c * i0 - s * i1;
        re[k] = s * r0 + c * r1;  im[k] = s * i0 + c * i1;
    }
}
// RX: [[c,-is],[-is,c]]
template <int LB>
__device__ __forceinline__ void g_rx(float* re, float* im, float c, float s) {
#pragma unroll
    for (int j = 0; j < TA; ++j) {
        if (j & (1 << LB)) continue;
        const int k = j | (1 << LB);
        float r0 = re[j], i0 = im[j], r1 = re[k], i1 = im[k];
        re[j] = c * r0 + s * i1;  im[j] = c * i0 - s * r1;
        re[k] = c * r1 + s * i0;  im[k] = c * i1 - s * r0;
    }
}
// CNOT control local LC, target local LT: pure register permutation
template <int LC, int LT>
__device__ __forceinline__ void g_cnot(float* re, float* im) {
#pragma unroll
    for (int j = 0; j < TA; ++j) {
        if (!((j >> LC) & 1) || ((j >> LT) & 1)) continue;
        const int k = j | (1 << LT);
        float tr = re[j], ti = im[j];
        re[j] = re[k]; im[j] = im[k];
        re[k] = tr;    im[k] = ti;
    }
}

// qubit q <-> bit position 13-q. Ring CNOTs in bit terms, in order:
// (13,12)(12,11)...(1,0)(0,13). Per layer, 5 rounds:
// R1{13,12,11,10} R2{10,9,8,7} R3{7,6,5,4} R4{4,3,2,1} R5{13,12,1,0}.
// Embedding RYs are folded into layer-0's rounds (commute with gates on
// other qubits; per-qubit RY precedes RX in the same round).
__attribute__((amdgpu_waves_per_eu(4, 4)))
__global__ void __launch_bounds__(NT) qsim_kernel(const float* __restrict__ x,
                                                  const float* __restrict__ w,
                                                  float* __restrict__ out) {
    __shared__ float2 sSt[DIM];          // 128 KB interleaved (re,im)
    __shared__ float sC[56], sS[56];     // [0..13]=RY embed, 14+l*14+q = RX
    __shared__ float sRed[NW][NQ];

    const int tid = threadIdx.x;
    const int b = blockIdx.x;

    if (tid < 14) {
        float th = tanhf(x[b * NQ + tid]) * 1.57079632679489662f;
        sC[tid] = cosf(th); sS[tid] = sinf(th);
    } else if (tid < 56) {
        float th = w[tid - 14] * 0.5f;
        sC[tid] = cosf(th); sS[tid] = sinf(th);
    }
    __syncthreads();

    float re[TA], im[TA];

    // ================= layer 0 (with embedding folded in) =================
    {   // R1 {13,12,11,10}: init + RY q0-3 + RX q0-3 + CNOT(13,12)(12,11)(11,10)
        using T = Tile4<13, 12, 11, 10>;
#pragma unroll
        for (int j = 0; j < TA; ++j) { re[j] = 0.f; im[j] = 0.f; }
        if (tid == 0) re[0] = 1.f;
        g_ry<0>(re, im, sC[0], sS[0]);
        g_ry<1>(re, im, sC[1], sS[1]);
        g_ry<2>(re, im, sC[2], sS[2]);
        g_ry<3>(re, im, sC[3], sS[3]);
        g_rx<0>(re, im, sC[14], sS[14]);
        g_rx<1>(re, im, sC[15], sS[15]);
        g_rx<2>(re, im, sC[16], sS[16]);
        g_rx<3>(re, im, sC[17], sS[17]);
        g_cnot<0, 1>(re, im);
        g_cnot<1, 2>(re, im);
        g_cnot<2, 3>(re, im);
        store_tile<T>(sSt, swz(T::base_idx(tid)), re, im);
    }
    __syncthreads();
    {   // R2 {10,9,8,7}: RY q4-6 + RX q4-6 + CNOT(10,9)(9,8)(8,7)
        using T = Tile4<10, 9, 8, 7>;
        const int pb = swz(T::base_idx(tid));
        load_tile<T>(sSt, pb, re, im);
        g_ry<1>(re, im, sC[4], sS[4]);
        g_ry<2>(re, im, sC[5], sS[5]);
        g_ry<3>(re, im, sC[6], sS[6]);
        g_rx<1>(re, im, sC[18], sS[18]);
        g_rx<2>(re, im, sC[19], sS[19]);
        g_rx<3>(re, im, sC[20], sS[20]);
        g_cnot<0, 1>(re, im);
        g_cnot<1, 2>(re, im);
        g_cnot<2, 3>(re, im);
        store_tile<T>(sSt, pb, re, im);
    }
    __syncthreads();
    {   // R3 {7,6,5,4}: RY q7-9 + RX q7-9 + CNOT(7,6)(6,5)(5,4)
        using T = Tile4<7, 6, 5, 4>;
        const int pb = swz(T::base_idx(tid));
        load_tile<T>(sSt, pb, re, im);
        g_ry<1>(re, im, sC[7], sS[7]);
        g_ry<2>(re, im, sC[8], sS[8]);
        g_ry<3>(re, im, sC[9], sS[9]);
        g_rx<1>(re, im, sC[21], sS[21]);
        g_rx<2>(re, im, sC[22], sS[22]);
        g_rx<3>(re, im, sC[23], sS[23]);
        g_cnot<0, 1>(re, im);
        g_cnot<1, 2>(re, im);
        g_cnot<2, 3>(re, im);
        store_tile<T>(sSt, pb, re, im);
    }
    __syncthreads();
    {   // R4 {4,3,2,1}: RY q10-12 + RX q10-12 + CNOT(4,3)(3,2)(2,1)
        using T = Tile4<4, 3, 2, 1>;
        const int pb = swz(T::base_idx(tid));
        load_tile<T>(sSt, pb, re, im);
        g_ry<1>(re, im, sC[10], sS[10]);
        g_ry<2>(re, im, sC[11], sS[11]);
        g_ry<3>(re, im, sC[12], sS[12]);
        g_rx<1>(re, im, sC[24], sS[24]);
        g_rx<2>(re, im, sC[25], sS[25]);
        g_rx<3>(re, im, sC[26], sS[26]);
        g_cnot<0, 1>(re, im);
        g_cnot<1, 2>(re, im);
        g_cnot<2, 3>(re, im);
        store_tile<T>(sSt, pb, re, im);
    }
    __syncthreads();
    {   // R5 {13,12,1,0}: RY q13 + RX q13 + CNOT(1,0)=<2,3> + CNOT(0,13)=<3,0>
        using T = Tile4<13, 12, 1, 0>;
        const int pb = swz(T::base_idx(tid));
        load_tile<T>(sSt, pb, re, im);
        g_ry<3>(re, im, sC[13], sS[13]);
        g_rx<3>(re, im, sC[27], sS[27]);
        g_cnot<2, 3>(re, im);
        g_cnot<3, 0>(re, im);
        store_tile<T>(sSt, pb, re, im);
    }
    __syncthreads();

    // ================= layers 1,2 =================
#pragma unroll 1
    for (int l = 1; l < 3; ++l) {
        const int s0 = 14 + l * NQ;
        {   // R1
            using T = Tile4<13, 12, 11, 10>;
            const int pb = swz(T::base_idx(tid));
            load_tile<T>(sSt, pb, re, im);
            g_rx<0>(re, im, sC[s0 + 0], sS[s0 + 0]);
            g_rx<1>(re, im, sC[s0 + 1], sS[s0 + 1]);
            g_rx<2>(re, im, sC[s0 + 2], sS[s0 + 2]);
            g_rx<3>(re, im, sC[s0 + 3], sS[s0 + 3]);
            g_cnot<0, 1>(re, im);
            g_cnot<1, 2>(re, im);
            g_cnot<2, 3>(re, im);
            store_tile<T>(sSt, pb, re, im);
        }
        __syncthreads();
        {   // R2
            using T = Tile4<10, 9, 8, 7>;
            const int pb = swz(T::base_idx(tid));
            load_tile<T>(sSt, pb, re, im);
            g_rx<1>(re, im, sC[s0 + 4], sS[s0 + 4]);
            g_rx<2>(re, im, sC[s0 + 5], sS[s0 + 5]);
            g_rx<3>(re, im, sC[s0 + 6], sS[s0 + 6]);
            g_cnot<0, 1>(re, im);
            g_cnot<1, 2>(re, im);
            g_cnot<2, 3>(re, im);
            store_tile<T>(sSt, pb, re, im);
        }
        __syncthreads();
        {   // R3
            using T = Tile4<7, 6, 5, 4>;
            const int pb = swz(T::base_idx(tid));
            load_tile<T>(sSt, pb, re, im);
            g_rx<1>(re, im, sC[s0 + 7], sS[s0 + 7]);
            g_rx<2>(re, im, sC[s0 + 8], sS[s0 + 8]);
            g_rx<3>(re, im, sC[s0 + 9], sS[s0 + 9]);
            g_cnot<0, 1>(re, im);
            g_cnot<1, 2>(re, im);
            g_cnot<2, 3>(re, im);
            store_tile<T>(sSt, pb, re, im);
        }
        __syncthreads();
        {   // R4
            using T = Tile4<4, 3, 2, 1>;
            const int pb = swz(T::base_idx(tid));
            load_tile<T>(sSt, pb, re, im);
            g_rx<1>(re, im, sC[s0 + 10], sS[s0 + 10]);
            g_rx<2>(re, im, sC[s0 + 11], sS[s0 + 11]);
            g_rx<3>(re, im, sC[s0 + 12], sS[s0 + 12]);
            g_cnot<0, 1>(re, im);
            g_cnot<1, 2>(re, im);
            g_cnot<2, 3>(re, im);
            store_tile<T>(sSt, pb, re, im);
        }
        __syncthreads();
        {   // R5
            using T = Tile4<13, 12, 1, 0>;
            const int pb = swz(T::base_idx(tid));
            load_tile<T>(sSt, pb, re, im);
            g_rx<3>(re, im, sC[s0 + 13], sS[s0 + 13]);
            g_cnot<2, 3>(re, im);
            g_cnot<3, 0>(re, im);
            if (l == 1) store_tile<T>(sSt, pb, re, im);
        }
        if (l == 1) __syncthreads();
    }

    // ====== expvals from final registers (tile {13,12,1,0}) ======
    float Stot = 0.f, Sa = 0.f, Sb = 0.f, Sc = 0.f, Sd = 0.f;
#pragma unroll
    for (int j = 0; j < TA; ++j) {
        float pj = re[j] * re[j] + im[j] * im[j];
        Stot += pj;
        Sa += (j & 1) ? -pj : pj;   // bit 13 (q0)
        Sb += (j & 2) ? -pj : pj;   // bit 12 (q1)
        Sc += (j & 4) ? -pj : pj;   // bit 1  (q12)
        Sd += (j & 8) ? -pj : pj;   // bit 0  (q13)
    }
    const int base = Tile4<13, 12, 1, 0>::base_idx(tid);  // bits 2..11 from tid
    float ev[NQ];
#pragma unroll
    for (int q = 0; q < NQ; ++q) {
        const int pt = NQ - 1 - q;
        float v;
        if (pt == 13)      v = Sa;
        else if (pt == 12) v = Sb;
        else if (pt == 1)  v = Sc;
        else if (pt == 0)  v = Sd;
        else v = ((base >> pt) & 1) ? -Stot : Stot;
        ev[q] = v;
    }
#pragma unroll
    for (int q = 0; q < NQ; ++q) {
#pragma unroll
        for (int o = 32; o > 0; o >>= 1) ev[q] += __shfl_down(ev[q], o);
    }
    const int wv = tid >> 6, ln = tid & 63;
    if (ln == 0) {
#pragma unroll
        for (int q = 0; q < NQ; ++q) sRed[wv][q] = ev[q];
    }
    __syncthreads();
    if (tid < NQ) {
        float acc = 0.f;
#pragma unroll
        for (int k = 0; k < NW; ++k) acc += sRed[k][tid];
        out[b * NQ + tid] = acc;
    }
}

extern "C" void kernel_launch(void* const* d_in, const int* in_sizes, int n_in,
                              void* d_out, int out_size, void* d_ws, size_t ws_size,
                              hipStream_t stream) {
    const float* x = (const float*)d_in[0];   // (256, 14) float32
    const float* w = (const float*)d_in[1];   // (3, 14) float32
    float* out = (float*)d_out;               // (256, 14) float32
    qsim_kernel<<<256, NT, 0, stream>>>(x, w, out);
}

// Round 4
// 93.365 us; speedup vs baseline: 2.3981x; 1.0563x over previous
//
#include <hip/hip_runtime.h>
#include <math.h>

#define NQ 14
#define DIM (1 << NQ)      // 16384 amplitudes
#define NT 1024            // 16 waves per block
#define TA 16              // amplitudes per thread (4-bit tile)
#define NW (NT / 64)

// State tile lives in an ext_vector -> first-class SSA value, never alloca'd,
// guaranteed VGPR-resident (fix for the 32 MB scratch traffic seen in r2/r3).
typedef float v16f __attribute__((ext_vector_type(16)));

// Linear bank swizzle: phys = idx ^ ((idx>>5)&31). Analytically verified: every
// round's wave64 b64 access hits each bank-pair exactly 4x (the minimum).
__host__ __device__ constexpr int swz(int idx) { return idx ^ ((idx >> 5) & 31); }

// Tile over 4 bit-positions; local j-bit k lives at global bit Pk. The other
// 10 index bits come from tid, scattered ascending into the complement.
template <int P0, int P1, int P2, int P3>
struct Tile4 {
    static constexpr int PMASK = (1 << P0) | (1 << P1) | (1 << P2) | (1 << P3);
    static __device__ __forceinline__ int base_idx(int t) {
        int idx = 0, tb = 0;
#pragma unroll
        for (int p = 0; p < NQ; ++p)
            if (!((PMASK >> p) & 1)) { idx |= ((t >> tb) & 1) << p; ++tb; }
        return idx;
    }
    static constexpr int off(int j) {
        return ((j & 1) << P0) | (((j >> 1) & 1) << P1) |
               (((j >> 2) & 1) << P2) | (((j >> 3) & 1) << P3);
    }
};

template <class T>
__device__ __forceinline__ void load_tile(const float2* s, int pb, v16f& re, v16f& im) {
#pragma unroll
    for (int j = 0; j < TA; ++j) {
        float2 v = s[pb ^ swz(T::off(j))];
        re[j] = v.x; im[j] = v.y;
    }
}
template <class T>
__device__ __forceinline__ void store_tile(float2* s, int pb, v16f re, v16f im) {
#pragma unroll
    for (int j = 0; j < TA; ++j)
        s[pb ^ swz(T::off(j))] = make_float2(re[j], im[j]);
}

// RY: [[c,-s],[s,c]] on local bit LB (register-only)
template <int LB>
__device__ __forceinline__ void g_ry(v16f& re, v16f& im, float c, float s) {
#pragma unroll
    for (int j = 0; j < TA; ++j) {
        if (j & (1 << LB)) continue;
        const int k = j | (1 << LB);
        float r0 = re[j], i0 = im[j], r1 = re[k], i1 = im[k];
        re[j] = c * r0 - s * r1;  im[j] = c * i0 - s * i1;
        re[k] = s * r0 + c * r1;  im[k] = s * i0 + c * i1;
    }
}
// RX: [[c,-is],[-is,c]]
template <int LB>
__device__ __forceinline__ void g_rx(v16f& re, v16f& im, float c, float s) {
#pragma unroll
    for (int j = 0; j < TA; ++j) {
        if (j & (1 << LB)) continue;
        const int k = j | (1 << LB);
        float r0 = re[j], i0 = im[j], r1 = re[k], i1 = im[k];
        re[j] = c * r0 + s * i1;  im[j] = c * i0 - s * r1;
        re[k] = c * r1 + s * i0;  im[k] = c * i1 - s * r0;
    }
}
// CNOT control local LC, target local LT: pure register permutation
template <int LC, int LT>
__device__ __forceinline__ void g_cnot(v16f& re, v16f& im) {
#pragma unroll
    for (int j = 0; j < TA; ++j) {
        if (!((j >> LC) & 1) || ((j >> LT) & 1)) continue;
        const int k = j | (1 << LT);
        float tr = re[j], ti = im[j];
        re[j] = re[k]; im[j] = im[k];
        re[k] = tr;    im[k] = ti;
    }
}

// qubit q <-> bit position 13-q. Ring CNOTs in bit terms, in order:
// (13,12)(12,11)...(1,0)(0,13). Per layer, 5 rounds:
// R1{13,12,11,10} R2{10,9,8,7} R3{7,6,5,4} R4{4,3,2,1} R5{13,12,1,0}.
// Embedding RYs folded into layer-0's rounds (commute with gates on other
// qubits; per-qubit RY precedes RX within its round).
__global__ void __launch_bounds__(NT) qsim_kernel(const float* __restrict__ x,
                                                  const float* __restrict__ w,
                                                  float* __restrict__ out) {
    __shared__ float2 sSt[DIM];          // 128 KB interleaved (re,im)
    __shared__ float sC[56], sS[56];     // [0..13]=RY embed, 14+l*14+q = RX
    __shared__ float sRed[NW][NQ];

    const int tid = threadIdx.x;
    const int b = blockIdx.x;

    if (tid < 14) {
        float th = tanhf(x[b * NQ + tid]) * 1.57079632679489662f;
        sC[tid] = cosf(th); sS[tid] = sinf(th);
    } else if (tid < 56) {
        float th = w[tid - 14] * 0.5f;
        sC[tid] = cosf(th); sS[tid] = sinf(th);
    }
    __syncthreads();

    v16f re, im;

    // ================= layer 0 (embedding folded in) =================
    {   // R1 {13,12,11,10}: init + RY q0-3 + RX q0-3 + CNOT(13,12)(12,11)(11,10)
        using T = Tile4<13, 12, 11, 10>;
#pragma unroll
        for (int j = 0; j < TA; ++j) { re[j] = 0.f; im[j] = 0.f; }
        if (tid == 0) re[0] = 1.f;
        g_ry<0>(re, im, sC[0], sS[0]);
        g_ry<1>(re, im, sC[1], sS[1]);
        g_ry<2>(re, im, sC[2], sS[2]);
        g_ry<3>(re, im, sC[3], sS[3]);
        g_rx<0>(re, im, sC[14], sS[14]);
        g_rx<1>(re, im, sC[15], sS[15]);
        g_rx<2>(re, im, sC[16], sS[16]);
        g_rx<3>(re, im, sC[17], sS[17]);
        g_cnot<0, 1>(re, im);
        g_cnot<1, 2>(re, im);
        g_cnot<2, 3>(re, im);
        store_tile<T>(sSt, swz(T::base_idx(tid)), re, im);
    }
    __syncthreads();
    {   // R2 {10,9,8,7}: RY q4-6 + RX q4-6 + CNOT(10,9)(9,8)(8,7)
        using T = Tile4<10, 9, 8, 7>;
        const int pb = swz(T::base_idx(tid));
        load_tile<T>(sSt, pb, re, im);
        g_ry<1>(re, im, sC[4], sS[4]);
        g_ry<2>(re, im, sC[5], sS[5]);
        g_ry<3>(re, im, sC[6], sS[6]);
        g_rx<1>(re, im, sC[18], sS[18]);
        g_rx<2>(re, im, sC[19], sS[19]);
        g_rx<3>(re, im, sC[20], sS[20]);
        g_cnot<0, 1>(re, im);
        g_cnot<1, 2>(re, im);
        g_cnot<2, 3>(re, im);
        store_tile<T>(sSt, pb, re, im);
    }
    __syncthreads();
    {   // R3 {7,6,5,4}: RY q7-9 + RX q7-9 + CNOT(7,6)(6,5)(5,4)
        using T = Tile4<7, 6, 5, 4>;
        const int pb = swz(T::base_idx(tid));
        load_tile<T>(sSt, pb, re, im);
        g_ry<1>(re, im, sC[7], sS[7]);
        g_ry<2>(re, im, sC[8], sS[8]);
        g_ry<3>(re, im, sC[9], sS[9]);
        g_rx<1>(re, im, sC[21], sS[21]);
        g_rx<2>(re, im, sC[22], sS[22]);
        g_rx<3>(re, im, sC[23], sS[23]);
        g_cnot<0, 1>(re, im);
        g_cnot<1, 2>(re, im);
        g_cnot<2, 3>(re, im);
        store_tile<T>(sSt, pb, re, im);
    }
    __syncthreads();
    {   // R4 {4,3,2,1}: RY q10-12 + RX q10-12 + CNOT(4,3)(3,2)(2,1)
        using T = Tile4<4, 3, 2, 1>;
        const int pb = swz(T::base_idx(tid));
        load_tile<T>(sSt, pb, re, im);
        g_ry<1>(re, im, sC[10], sS[10]);
        g_ry<2>(re, im, sC[11], sS[11]);
        g_ry<3>(re, im, sC[12], sS[12]);
        g_rx<1>(re, im, sC[24], sS[24]);
        g_rx<2>(re, im, sC[25], sS[25]);
        g_rx<3>(re, im, sC[26], sS[26]);
        g_cnot<0, 1>(re, im);
        g_cnot<1, 2>(re, im);
        g_cnot<2, 3>(re, im);
        store_tile<T>(sSt, pb, re, im);
    }
    __syncthreads();
    {   // R5 {13,12,1,0}: RY q13 + RX q13 + CNOT(1,0)=<2,3> + CNOT(0,13)=<3,0>
        using T = Tile4<13, 12, 1, 0>;
        const int pb = swz(T::base_idx(tid));
        load_tile<T>(sSt, pb, re, im);
        g_ry<3>(re, im, sC[13], sS[13]);
        g_rx<3>(re, im, sC[27], sS[27]);
        g_cnot<2, 3>(re, im);
        g_cnot<3, 0>(re, im);
        store_tile<T>(sSt, pb, re, im);
    }
    __syncthreads();

    // ================= layers 1,2 =================
#pragma unroll 1
    for (int l = 1; l < 3; ++l) {
        const int s0 = 14 + l * NQ;
        {   // R1
            using T = Tile4<13, 12, 11, 10>;
            const int pb = swz(T::base_idx(tid));
            load_tile<T>(sSt, pb, re, im);
            g_rx<0>(re, im, sC[s0 + 0], sS[s0 + 0]);
            g_rx<1>(re, im, sC[s0 + 1], sS[s0 + 1]);
            g_rx<2>(re, im, sC[s0 + 2], sS[s0 + 2]);
            g_rx<3>(re, im, sC[s0 + 3], sS[s0 + 3]);
            g_cnot<0, 1>(re, im);
            g_cnot<1, 2>(re, im);
            g_cnot<2, 3>(re, im);
            store_tile<T>(sSt, pb, re, im);
        }
        __syncthreads();
        {   // R2
            using T = Tile4<10, 9, 8, 7>;
            const int pb = swz(T::base_idx(tid));
            load_tile<T>(sSt, pb, re, im);
            g_rx<1>(re, im, sC[s0 + 4], sS[s0 + 4]);
            g_rx<2>(re, im, sC[s0 + 5], sS[s0 + 5]);
            g_rx<3>(re, im, sC[s0 + 6], sS[s0 + 6]);
            g_cnot<0, 1>(re, im);
            g_cnot<1, 2>(re, im);
            g_cnot<2, 3>(re, im);
            store_tile<T>(sSt, pb, re, im);
        }
        __syncthreads();
        {   // R3
            using T = Tile4<7, 6, 5, 4>;
            const int pb = swz(T::base_idx(tid));
            load_tile<T>(sSt, pb, re, im);
            g_rx<1>(re, im, sC[s0 + 7], sS[s0 + 7]);
            g_rx<2>(re, im, sC[s0 + 8], sS[s0 + 8]);
            g_rx<3>(re, im, sC[s0 + 9], sS[s0 + 9]);
            g_cnot<0, 1>(re, im);
            g_cnot<1, 2>(re, im);
            g_cnot<2, 3>(re, im);
            store_tile<T>(sSt, pb, re, im);
        }
        __syncthreads();
        {   // R4
            using T = Tile4<4, 3, 2, 1>;
            const int pb = swz(T::base_idx(tid));
            load_tile<T>(sSt, pb, re, im);
            g_rx<1>(re, im, sC[s0 + 10], sS[s0 + 10]);
            g_rx<2>(re, im, sC[s0 + 11], sS[s0 + 11]);
            g_rx<3>(re, im, sC[s0 + 12], sS[s0 + 12]);
            g_cnot<0, 1>(re, im);
            g_cnot<1, 2>(re, im);
            g_cnot<2, 3>(re, im);
            store_tile<T>(sSt, pb, re, im);
        }
        __syncthreads();
        {   // R5
            using T = Tile4<13, 12, 1, 0>;
            const int pb = swz(T::base_idx(tid));
            load_tile<T>(sSt, pb, re, im);
            g_rx<3>(re, im, sC[s0 + 13], sS[s0 + 13]);
            g_cnot<2, 3>(re, im);
            g_cnot<3, 0>(re, im);
            if (l == 1) store_tile<T>(sSt, pb, re, im);
        }
        if (l == 1) __syncthreads();
    }

    // ====== expvals from final registers (tile {13,12,1,0}) ======
    float Stot = 0.f, Sa = 0.f, Sb = 0.f, Sc = 0.f, Sd = 0.f;
#pragma unroll
    for (int j = 0; j < TA; ++j) {
        float pj = re[j] * re[j] + im[j] * im[j];
        Stot += pj;
        Sa += (j & 1) ? -pj : pj;   // bit 13 (q0)
        Sb += (j & 2) ? -pj : pj;   // bit 12 (q1)
        Sc += (j & 4) ? -pj : pj;   // bit 1  (q12)
        Sd += (j & 8) ? -pj : pj;   // bit 0  (q13)
    }
    const int base = Tile4<13, 12, 1, 0>::base_idx(tid);  // bits 2..11 from tid
    float ev[NQ];
#pragma unroll
    for (int q = 0; q < NQ; ++q) {
        const int pt = NQ - 1 - q;
        float v;
        if (pt == 13)      v = Sa;
        else if (pt == 12) v = Sb;
        else if (pt == 1)  v = Sc;
        else if (pt == 0)  v = Sd;
        else v = ((base >> pt) & 1) ? -Stot : Stot;
        ev[q] = v;
    }
#pragma unroll
    for (int q = 0; q < NQ; ++q) {
#pragma unroll
        for (int o = 32; o > 0; o >>= 1) ev[q] += __shfl_down(ev[q], o);
    }
    const int wv = tid >> 6, ln = tid & 63;
    if (ln == 0) {
#pragma unroll
        for (int q = 0; q < NQ; ++q) sRed[wv][q] = ev[q];
    }
    __syncthreads();
    if (tid < NQ) {
        float acc = 0.f;
#pragma unroll
        for (int k = 0; k < NW; ++k) acc += sRed[k][tid];
        out[b * NQ + tid] = acc;
    }
}

extern "C" void kernel_launch(void* const* d_in, const int* in_sizes, int n_in,
                              void* d_out, int out_size, void* d_ws, size_t ws_size,
                              hipStream_t stream) {
    const float* x = (const float*)d_in[0];   // (256, 14) float32
    const float* w = (const float*)d_in[1];   // (3, 14) float32
    float* out = (float*)d_out;               // (256, 14) float32
    qsim_kernel<<<256, NT, 0, stream>>>(x, w, out);
}

// Round 5
// 92.887 us; speedup vs baseline: 2.4104x; 1.0051x over previous
//
#include <hip/hip_runtime.h>
#include <math.h>

#define NQ 14
#define DIM (1 << NQ)      // 16384 amplitudes
#define NT 1024            // 16 waves per block
#define TA 16              // amplitudes per thread (4-bit tile)
#define NW (NT / 64)

// State tile in an ext_vector -> first-class SSA, never alloca'd.
typedef float v16f __attribute__((ext_vector_type(16)));

// Linear bank swizzle: phys = idx ^ ((idx>>5)&31).
__host__ __device__ constexpr int swz(int idx) { return idx ^ ((idx >> 5) & 31); }

// Tile over 4 bit-positions; local j-bit k lives at global bit Pk. The other
// 10 index bits come from tid, scattered ascending into the complement.
template <int P0, int P1, int P2, int P3>
struct Tile4 {
    static constexpr int PMASK = (1 << P0) | (1 << P1) | (1 << P2) | (1 << P3);
    static __device__ __forceinline__ int base_idx(int t) {
        int idx = 0, tb = 0;
#pragma unroll
        for (int p = 0; p < NQ; ++p)
            if (!((PMASK >> p) & 1)) { idx |= ((t >> tb) & 1) << p; ++tb; }
        return idx;
    }
    static constexpr int off(int j) {
        return ((j & 1) << P0) | (((j >> 1) & 1) << P1) |
               (((j >> 2) & 1) << P2) | (((j >> 3) & 1) << P3);
    }
};

template <class T>
__device__ __forceinline__ void load_tile(const float2* s, int pb, v16f& re, v16f& im) {
#pragma unroll
    for (int j = 0; j < TA; ++j) {
        float2 v = s[pb ^ swz(T::off(j))];
        re[j] = v.x; im[j] = v.y;
    }
}
template <class T>
__device__ __forceinline__ void store_tile(float2* s, int pb, v16f re, v16f im) {
#pragma unroll
    for (int j = 0; j < TA; ++j)
        s[pb ^ swz(T::off(j))] = make_float2(re[j], im[j]);
}

// RY: [[c,-s],[s,c]] on local bit LB (register-only)
template <int LB>
__device__ __forceinline__ void g_ry(v16f& re, v16f& im, float c, float s) {
#pragma unroll
    for (int j = 0; j < TA; ++j) {
        if (j & (1 << LB)) continue;
        const int k = j | (1 << LB);
        float r0 = re[j], i0 = im[j], r1 = re[k], i1 = im[k];
        re[j] = c * r0 - s * r1;  im[j] = c * i0 - s * i1;
        re[k] = s * r0 + c * r1;  im[k] = s * i0 + c * i1;
    }
}
// RX: [[c,-is],[-is,c]]
template <int LB>
__device__ __forceinline__ void g_rx(v16f& re, v16f& im, float c, float s) {
#pragma unroll
    for (int j = 0; j < TA; ++j) {
        if (j & (1 << LB)) continue;
        const int k = j | (1 << LB);
        float r0 = re[j], i0 = im[j], r1 = re[k], i1 = im[k];
        re[j] = c * r0 + s * i1;  im[j] = c * i0 - s * r1;
        re[k] = c * r1 + s * i0;  im[k] = c * i1 - s * r0;
    }
}
// CNOT control local LC, target local LT: pure register permutation
template <int LC, int LT>
__device__ __forceinline__ void g_cnot(v16f& re, v16f& im) {
#pragma unroll
    for (int j = 0; j < TA; ++j) {
        if (!((j >> LC) & 1) || ((j >> LT) & 1)) continue;
        const int k = j | (1 << LT);
        float tr = re[j], ti = im[j];
        re[j] = re[k]; im[j] = im[k];
        re[k] = tr;    im[k] = ti;
    }
}

// qubit q <-> bit position 13-q. Ring CNOTs in bit terms, in order:
// (13,12)(12,11)...(1,0)(0,13). Per layer, 5 rounds:
// R1{13,12,11,10} R2{10,9,8,7} R3{7,6,5,4} R4{4,3,2,1} R5{13,12,1,0}.
// Embedding RYs folded into layer-0's rounds.
//
// __launch_bounds__(1024, 4): 4 waves/EU * 4 EU / 16 waves-per-block = 1
// block/CU (the LDS limit anyway) -> VGPR cap 128, stops the allocator's
// 8-waves/EU heuristic that clamped to 64 VGPRs and spilled ~11 regs (the
// 11.3 MB WRITE_SIZE seen in r4).
__global__ void __launch_bounds__(NT, 4) qsim_kernel(const float* __restrict__ x,
                                                     const float* __restrict__ w,
                                                     float* __restrict__ out) {
    __shared__ float2 sSt[DIM];          // 128 KB interleaved (re,im)
    __shared__ float sC[56], sS[56];     // [0..13]=RY embed, 14+l*14+q = RX
    __shared__ float sRed[NW][NQ];

    const int tid = threadIdx.x;
    const int b = blockIdx.x;

    if (tid < 14) {
        float th = tanhf(x[b * NQ + tid]) * 1.57079632679489662f;
        sC[tid] = cosf(th); sS[tid] = sinf(th);
    } else if (tid < 56) {
        float th = w[tid - 14] * 0.5f;
        sC[tid] = cosf(th); sS[tid] = sinf(th);
    }
    __syncthreads();

    v16f re, im;

    // ================= layer 0 (embedding folded in) =================
    {   // R1 {13,12,11,10}: init + RY q0-3 + RX q0-3 + CNOT(13,12)(12,11)(11,10)
        using T = Tile4<13, 12, 11, 10>;
#pragma unroll
        for (int j = 0; j < TA; ++j) { re[j] = 0.f; im[j] = 0.f; }
        if (tid == 0) re[0] = 1.f;
        g_ry<0>(re, im, sC[0], sS[0]);
        g_ry<1>(re, im, sC[1], sS[1]);
        g_ry<2>(re, im, sC[2], sS[2]);
        g_ry<3>(re, im, sC[3], sS[3]);
        g_rx<0>(re, im, sC[14], sS[14]);
        g_rx<1>(re, im, sC[15], sS[15]);
        g_rx<2>(re, im, sC[16], sS[16]);
        g_rx<3>(re, im, sC[17], sS[17]);
        g_cnot<0, 1>(re, im);
        g_cnot<1, 2>(re, im);
        g_cnot<2, 3>(re, im);
        store_tile<T>(sSt, swz(T::base_idx(tid)), re, im);
    }
    __syncthreads();
    {   // R2 {10,9,8,7}: RY q4-6 + RX q4-6 + CNOT(10,9)(9,8)(8,7)
        using T = Tile4<10, 9, 8, 7>;
        const int pb = swz(T::base_idx(tid));
        load_tile<T>(sSt, pb, re, im);
        g_ry<1>(re, im, sC[4], sS[4]);
        g_ry<2>(re, im, sC[5], sS[5]);
        g_ry<3>(re, im, sC[6], sS[6]);
        g_rx<1>(re, im, sC[18], sS[18]);
        g_rx<2>(re, im, sC[19], sS[19]);
        g_rx<3>(re, im, sC[20], sS[20]);
        g_cnot<0, 1>(re, im);
        g_cnot<1, 2>(re, im);
        g_cnot<2, 3>(re, im);
        store_tile<T>(sSt, pb, re, im);
    }
    __syncthreads();
    {   // R3 {7,6,5,4}: RY q7-9 + RX q7-9 + CNOT(7,6)(6,5)(5,4)
        using T = Tile4<7, 6, 5, 4>;
        const int pb = swz(T::base_idx(tid));
        load_tile<T>(sSt, pb, re, im);
        g_ry<1>(re, im, sC[7], sS[7]);
        g_ry<2>(re, im, sC[8], sS[8]);
        g_ry<3>(re, im, sC[9], sS[9]);
        g_rx<1>(re, im, sC[21], sS[21]);
        g_rx<2>(re, im, sC[22], sS[22]);
        g_rx<3>(re, im, sC[23], sS[23]);
        g_cnot<0, 1>(re, im);
        g_cnot<1, 2>(re, im);
        g_cnot<2, 3>(re, im);
        store_tile<T>(sSt, pb, re, im);
    }
    __syncthreads();
    {   // R4 {4,3,2,1}: RY q10-12 + RX q10-12 + CNOT(4,3)(3,2)(2,1)
        using T = Tile4<4, 3, 2, 1>;
        const int pb = swz(T::base_idx(tid));
        load_tile<T>(sSt, pb, re, im);
        g_ry<1>(re, im, sC[10], sS[10]);
        g_ry<2>(re, im, sC[11], sS[11]);
        g_ry<3>(re, im, sC[12], sS[12]);
        g_rx<1>(re, im, sC[24], sS[24]);
        g_rx<2>(re, im, sC[25], sS[25]);
        g_rx<3>(re, im, sC[26], sS[26]);
        g_cnot<0, 1>(re, im);
        g_cnot<1, 2>(re, im);
        g_cnot<2, 3>(re, im);
        store_tile<T>(sSt, pb, re, im);
    }
    __syncthreads();
    {   // R5 {13,12,1,0}: RY q13 + RX q13 + CNOT(1,0)=<2,3> + CNOT(0,13)=<3,0>
        using T = Tile4<13, 12, 1, 0>;
        const int pb = swz(T::base_idx(tid));
        load_tile<T>(sSt, pb, re, im);
        g_ry<3>(re, im, sC[13], sS[13]);
        g_rx<3>(re, im, sC[27], sS[27]);
        g_cnot<2, 3>(re, im);
        g_cnot<3, 0>(re, im);
        store_tile<T>(sSt, pb, re, im);
    }
    __syncthreads();

    // ================= layers 1,2 =================
#pragma unroll 1
    for (int l = 1; l < 3; ++l) {
        const int s0 = 14 + l * NQ;
        {   // R1
            using T = Tile4<13, 12, 11, 10>;
            const int pb = swz(T::base_idx(tid));
            load_tile<T>(sSt, pb, re, im);
            g_rx<0>(re, im, sC[s0 + 0], sS[s0 + 0]);
            g_rx<1>(re, im, sC[s0 + 1], sS[s0 + 1]);
            g_rx<2>(re, im, sC[s0 + 2], sS[s0 + 2]);
            g_rx<3>(re, im, sC[s0 + 3], sS[s0 + 3]);
            g_cnot<0, 1>(re, im);
            g_cnot<1, 2>(re, im);
            g_cnot<2, 3>(re, im);
            store_tile<T>(sSt, pb, re, im);
        }
        __syncthreads();
        {   // R2
            using T = Tile4<10, 9, 8, 7>;
            const int pb = swz(T::base_idx(tid));
            load_tile<T>(sSt, pb, re, im);
            g_rx<1>(re, im, sC[s0 + 4], sS[s0 + 4]);
            g_rx<2>(re, im, sC[s0 + 5], sS[s0 + 5]);
            g_rx<3>(re, im, sC[s0 + 6], sS[s0 + 6]);
            g_cnot<0, 1>(re, im);
            g_cnot<1, 2>(re, im);
            g_cnot<2, 3>(re, im);
            store_tile<T>(sSt, pb, re, im);
        }
        __syncthreads();
        {   // R3
            using T = Tile4<7, 6, 5, 4>;
            const int pb = swz(T::base_idx(tid));
            load_tile<T>(sSt, pb, re, im);
            g_rx<1>(re, im, sC[s0 + 7], sS[s0 + 7]);
            g_rx<2>(re, im, sC[s0 + 8], sS[s0 + 8]);
            g_rx<3>(re, im, sC[s0 + 9], sS[s0 + 9]);
            g_cnot<0, 1>(re, im);
            g_cnot<1, 2>(re, im);
            g_cnot<2, 3>(re, im);
            store_tile<T>(sSt, pb, re, im);
        }
        __syncthreads();
        {   // R4
            using T = Tile4<4, 3, 2, 1>;
            const int pb = swz(T::base_idx(tid));
            load_tile<T>(sSt, pb, re, im);
            g_rx<1>(re, im, sC[s0 + 10], sS[s0 + 10]);
            g_rx<2>(re, im, sC[s0 + 11], sS[s0 + 11]);
            g_rx<3>(re, im, sC[s0 + 12], sS[s0 + 12]);
            g_cnot<0, 1>(re, im);
            g_cnot<1, 2>(re, im);
            g_cnot<2, 3>(re, im);
            store_tile<T>(sSt, pb, re, im);
        }
        __syncthreads();
        {   // R5
            using T = Tile4<13, 12, 1, 0>;
            const int pb = swz(T::base_idx(tid));
            load_tile<T>(sSt, pb, re, im);
            g_rx<3>(re, im, sC[s0 + 13], sS[s0 + 13]);
            g_cnot<2, 3>(re, im);
            g_cnot<3, 0>(re, im);
            if (l == 1) store_tile<T>(sSt, pb, re, im);
        }
        if (l == 1) __syncthreads();
    }

    // ====== expvals from final registers (tile {13,12,1,0}) ======
    float Stot = 0.f, Sa = 0.f, Sb = 0.f, Sc = 0.f, Sd = 0.f;
#pragma unroll
    for (int j = 0; j < TA; ++j) {
        float pj = re[j] * re[j] + im[j] * im[j];
        Stot += pj;
        Sa += (j & 1) ? -pj : pj;   // bit 13 (q0)
        Sb += (j & 2) ? -pj : pj;   // bit 12 (q1)
        Sc += (j & 4) ? -pj : pj;   // bit 1  (q12)
        Sd += (j & 8) ? -pj : pj;   // bit 0  (q13)
    }
    const int base = Tile4<13, 12, 1, 0>::base_idx(tid);  // bits 2..11 from tid
    float ev[NQ];
#pragma unroll
    for (int q = 0; q < NQ; ++q) {
        const int pt = NQ - 1 - q;
        float v;
        if (pt == 13)      v = Sa;
        else if (pt == 12) v = Sb;
        else if (pt == 1)  v = Sc;
        else if (pt == 0)  v = Sd;
        else v = ((base >> pt) & 1) ? -Stot : Stot;
        ev[q] = v;
    }
#pragma unroll
    for (int q = 0; q < NQ; ++q) {
#pragma unroll
        for (int o = 32; o > 0; o >>= 1) ev[q] += __shfl_down(ev[q], o);
    }
    const int wv = tid >> 6, ln = tid & 63;
    if (ln == 0) {
#pragma unroll
        for (int q = 0; q < NQ; ++q) sRed[wv][q] = ev[q];
    }
    __syncthreads();
    if (tid < NQ) {
        float acc = 0.f;
#pragma unroll
        for (int k = 0; k < NW; ++k) acc += sRed[k][tid];
        out[b * NQ + tid] = acc;
    }
}

extern "C" void kernel_launch(void* const* d_in, const int* in_sizes, int n_in,
                              void* d_out, int out_size, void* d_ws, size_t ws_size,
                              hipStream_t stream) {
    const float* x = (const float*)d_in[0];   // (256, 14) float32
    const float* w = (const float*)d_in[1];   // (3, 14) float32
    float* out = (float*)d_out;               // (256, 14) float32
    qsim_kernel<<<256, NT, 0, stream>>>(x, w, out);
}